// Round 3
// baseline (1049.053 us; speedup 1.0000x reference)
//
#include <hip/hip_runtime.h>
#include <hip/hip_bf16.h>

#define FDIM 64

// One thread per (edge, feature). f = lane & 63 so each wave handles exactly
// one edge; index loads are wave-uniform (L1 broadcast), src/agg accesses are
// fully coalesced 64-lane rows.
__global__ __launch_bounds__(256) void scatter_kernel(
    const float* __restrict__ src, const int* __restrict__ rows, const int* __restrict__ cols,
    float* __restrict__ agg, float* __restrict__ deg, int n, long long total)
{
    long long gid = (long long)blockIdx.x * 256 + threadIdx.x;
    if (gid >= total) return;
    int e = (int)(gid >> 6);
    int f = (int)(gid & 63);
    int r = rows[e], c = cols[e];
    // defensive clamp (guards against index-dtype surprises becoming OOB)
    r = min(max(r, 0), n - 1);
    c = min(max(c, 0), n - 1);
    atomicAdd(&agg[(long long)c * FDIM + f], src[(long long)r * FDIM + f]);
    if (f == 0) atomicAdd(&deg[c], 1.0f);
}

// 4 rows per 256-thread block; each wave owns one row (64 output cols).
// W, R staged in LDS. Optional relu (layer 1) / L2-normalize (layer 2).
template <bool RELU, bool NORM>
__global__ __launch_bounds__(256) void dense_kernel(
    const float* __restrict__ agg, const float* __restrict__ deg, const float* __restrict__ x,
    const float* __restrict__ W, const float* __restrict__ b,
    const float* __restrict__ R, float* __restrict__ out, int n)
{
    __shared__ float Ws[FDIM][FDIM];
    __shared__ float Rs[FDIM][FDIM];
    __shared__ float bs[FDIM];
    __shared__ float aRow[4][FDIM];
    __shared__ float xRow[4][FDIM];
    int tid = threadIdx.x;
    for (int i = tid; i < FDIM * FDIM; i += 256) {
        Ws[i >> 6][i & 63] = W[i];
        Rs[i >> 6][i & 63] = R[i];
    }
    if (tid < FDIM) bs[tid] = b[tid];
    int j = tid & 63, r = tid >> 6;
    int row = blockIdx.x * 4 + r;
    if (row < n) {
        float d = fmaxf(deg[row], 1.0f);
        aRow[r][j] = agg[(long long)row * FDIM + j] / d;
        xRow[r][j] = x[(long long)row * FDIM + j];
    }
    __syncthreads();
    if (row >= n) return;
    float acc = bs[j];
#pragma unroll
    for (int k = 0; k < FDIM; ++k)
        acc = fmaf(aRow[r][k], Ws[k][j], fmaf(xRow[r][k], Rs[k][j], acc));
    if (RELU) acc = fmaxf(acc, 0.0f);
    if (NORM) {
        float ss = acc * acc;
#pragma unroll
        for (int o = 32; o; o >>= 1) ss += __shfl_xor(ss, o, 64);
        acc *= 1.0f / fmaxf(sqrtf(ss), 1e-12f);
    }
    out[(long long)row * FDIM + j] = acc;
}

extern "C" void kernel_launch(void* const* d_in, const int* in_sizes, int n_in,
                              void* d_out, int out_size, void* d_ws, size_t ws_size,
                              hipStream_t stream)
{
    // Reference dtypes: all float tensors are float32; indices int32.
    const float* x  = (const float*)d_in[0];
    const int*   e0 = (const int*)d_in[1];
    const int*   e1 = (const int*)d_in[2];
    const float* W1 = (const float*)d_in[3];
    const float* b1 = (const float*)d_in[4];
    const float* R1 = (const float*)d_in[5];
    const float* W2 = (const float*)d_in[6];
    const float* b2 = (const float*)d_in[7];
    const float* R2 = (const float*)d_in[8];
    float* out = (float*)d_out;

    const int N = in_sizes[0] / FDIM;     // 50000
    const int E = in_sizes[1] / 2;        // 1600000

    // Workspace (fp32): agg[N*64] | deg[N]   (13.0 MB)
    float* agg = (float*)d_ws;
    float* deg = agg + (long long)N * FDIM;
    // Hidden layer h (fp32, N*64) lives in d_out — same size as the final
    // output; layer-2 scatter completes before layer-2 dense overwrites it,
    // and each dense thread reads its own row before writing it.
    float* h = out;

    const long long total = (long long)E * FDIM;
    const int sblocks = (int)((total + 255) / 256);
    const int dblocks = (N + 3) / 4;

    // ---- Layer 1: agg = segment_sum(x[row] -> col); h = relu(agg/deg @W1 + b1 + x@R1)
    hipMemsetAsync(agg, 0, ((size_t)N * FDIM + N) * sizeof(float), stream);
    scatter_kernel<<<sblocks, 256, 0, stream>>>(x, e0, e0 + E, agg, deg, N, total);
    dense_kernel<true, false><<<dblocks, 256, 0, stream>>>(agg, deg, x, W1, b1, R1, h, N);

    // ---- Layer 2: agg = segment_sum(h[row] -> col); out = normalize(agg/deg @W2 + b2 + h@R2)
    hipMemsetAsync(agg, 0, ((size_t)N * FDIM + N) * sizeof(float), stream);
    scatter_kernel<<<sblocks, 256, 0, stream>>>(h, e1, e1 + E, agg, deg, N, total);
    dense_kernel<false, true><<<dblocks, 256, 0, stream>>>(agg, deg, h, W2, b2, R2, out, N);
}

// Round 4
// 697.603 us; speedup vs baseline: 1.5038x; 1.5038x over previous
//
#include <hip/hip_runtime.h>
#include <hip/hip_bf16.h>

#define FDIM 64

__device__ __forceinline__ int clampi(int v, int n) { return min(max(v, 0), n - 1); }

// ------------------------- CSR build (per layer) ---------------------------

__global__ __launch_bounds__(256) void hist_kernel(
    const int* __restrict__ cols, int* __restrict__ hist, int n, int E)
{
    int e = blockIdx.x * 256 + threadIdx.x;
    if (e >= E) return;
    atomicAdd(&hist[clampi(cols[e], n)], 1);
}

// Single-block exclusive scan of hist[0..n-1] -> rowptr[0..n]; rowptr[n]=E.
__global__ __launch_bounds__(1024) void scan_kernel(
    const int* __restrict__ hist, int* __restrict__ rowptr, int n)
{
    __shared__ int wsum[16];
    __shared__ int carry;
    int tid = threadIdx.x, lane = tid & 63, wid = tid >> 6;
    if (tid == 0) carry = 0;
    __syncthreads();
    for (int base = 0; base < n; base += 1024) {
        int i = base + tid;
        int v = (i < n) ? hist[i] : 0;
        int s = v;
#pragma unroll
        for (int o = 1; o < 64; o <<= 1) { int t = __shfl_up(s, o, 64); if (lane >= o) s += t; }
        if (lane == 63) wsum[wid] = s;
        __syncthreads();
        if (wid == 0) {
            int ws_ = (lane < 16) ? wsum[lane] : 0;
#pragma unroll
            for (int o = 1; o < 16; o <<= 1) { int t = __shfl_up(ws_, o, 64); if (lane >= o) ws_ += t; }
            if (lane < 16) wsum[lane] = ws_;
        }
        __syncthreads();
        int woff = (wid > 0) ? wsum[wid - 1] : 0;
        int excl = carry + woff + s - v;
        if (i < n) rowptr[i] = excl;
        int ctot = wsum[15];
        __syncthreads();
        if (tid == 0) carry += ctot;
        __syncthreads();
    }
    if (threadIdx.x == 0) rowptr[n] = carry;
}

__global__ __launch_bounds__(256) void fill_kernel(
    const int* __restrict__ rows, const int* __restrict__ cols,
    const int* __restrict__ rowptr, int* __restrict__ cursor,
    int* __restrict__ csridx, int n, int E)
{
    int e = blockIdx.x * 256 + threadIdx.x;
    if (e >= E) return;
    int c = clampi(cols[e], n);
    int p = atomicAdd(&cursor[c], 1);
    csridx[rowptr[c] + p] = clampi(rows[e], n);
}

// ------------- Fused gather(mean) + dense (+relu / +L2 norm) ---------------
// One wave per node (grid-stride). Gather: 16 lanes x float4 per source row,
// 4 edges in flight per VMEM issue; cross-group combine via shfl_xor.
// Dense: W,R,b staged in LDS per block; agg/root rows via wave-local LDS.
template <bool RELU, bool NORM>
__global__ __launch_bounds__(256) void fused_sage_kernel(
    const int* __restrict__ rowptr, const int* __restrict__ csridx,
    const float* __restrict__ src,
    const float* __restrict__ W, const float* __restrict__ bvec,
    const float* __restrict__ R, float* __restrict__ out, int n)
{
    __shared__ float Ws[FDIM][FDIM];
    __shared__ float Rs[FDIM][FDIM];
    __shared__ float bs[FDIM];
    __shared__ float aRow[4][FDIM];
    __shared__ float xRow[4][FDIM];
    int tid = threadIdx.x;
    for (int i = tid; i < FDIM * FDIM; i += 256) {
        Ws[i >> 6][i & 63] = W[i];
        Rs[i >> 6][i & 63] = R[i];
    }
    if (tid < FDIM) bs[tid] = bvec[tid];
    __syncthreads();

    int lane = tid & 63, w = tid >> 6;
    int g = lane >> 4;        // edge sub-group 0..3
    int q = lane & 15;        // float4 chunk within row

    for (int node = blockIdx.x * 4 + w; node < n; node += gridDim.x * 4) {
        int beg = rowptr[node], end = rowptr[node + 1];
        float4 s4 = make_float4(0.f, 0.f, 0.f, 0.f);
        for (int base = beg; base < end; base += 64) {
            int cnt = end - base; if (cnt > 64) cnt = 64;
            int ei = base + lane;
            int myidx = (ei < end) ? csridx[ei] : 0;
            int steps = (cnt + 3) >> 2;
            for (int t = 0; t < steps; ++t) {
                int e = (t << 2) | g;
                int sidx = __shfl(myidx, e, 64);
                if (e < cnt) {
                    const float4* rp = (const float4*)(src + ((long long)sidx << 6));
                    float4 v = rp[q];
                    s4.x += v.x; s4.y += v.y; s4.z += v.z; s4.w += v.w;
                }
            }
        }
        // combine the 4 groups (lanes l, l^16, l^32, l^48 hold chunk-q partials)
#pragma unroll
        for (int o = 16; o < 64; o <<= 1) {
            s4.x += __shfl_xor(s4.x, o, 64);
            s4.y += __shfl_xor(s4.y, o, 64);
            s4.z += __shfl_xor(s4.z, o, 64);
            s4.w += __shfl_xor(s4.w, o, 64);
        }
        float dinv = 1.0f / fmaxf((float)(end - beg), 1.0f);
        if (g == 0) {
            aRow[w][q * 4 + 0] = s4.x * dinv;
            aRow[w][q * 4 + 1] = s4.y * dinv;
            aRow[w][q * 4 + 2] = s4.z * dinv;
            aRow[w][q * 4 + 3] = s4.w * dinv;
        }
        xRow[w][lane] = src[((long long)node << 6) + lane];
        // wave-local LDS RAW: ordered within the wave, no barrier needed
        float acc = bs[lane];
#pragma unroll
        for (int k = 0; k < FDIM; ++k)
            acc = fmaf(aRow[w][k], Ws[k][lane], fmaf(xRow[w][k], Rs[k][lane], acc));
        if (RELU) acc = fmaxf(acc, 0.0f);
        if (NORM) {
            float ss = acc * acc;
#pragma unroll
            for (int o = 32; o; o >>= 1) ss += __shfl_xor(ss, o, 64);
            acc *= 1.0f / fmaxf(sqrtf(ss), 1e-12f);
        }
        out[((long long)node << 6) + lane] = acc;
    }
}

// ----------------- Fallback (round-3 atomic path, 13.0 MB ws) --------------

__global__ __launch_bounds__(256) void scatter_kernel(
    const float* __restrict__ src, const int* __restrict__ rows, const int* __restrict__ cols,
    float* __restrict__ agg, float* __restrict__ deg, int n, long long total)
{
    long long gid = (long long)blockIdx.x * 256 + threadIdx.x;
    if (gid >= total) return;
    int e = (int)(gid >> 6);
    int f = (int)(gid & 63);
    int r = clampi(rows[e], n), c = clampi(cols[e], n);
    atomicAdd(&agg[(long long)c * FDIM + f], src[(long long)r * FDIM + f]);
    if (f == 0) atomicAdd(&deg[c], 1.0f);
}

template <bool RELU, bool NORM>
__global__ __launch_bounds__(256) void dense_kernel(
    const float* __restrict__ agg, const float* __restrict__ deg, const float* __restrict__ x,
    const float* __restrict__ W, const float* __restrict__ b,
    const float* __restrict__ R, float* __restrict__ out, int n)
{
    __shared__ float Ws[FDIM][FDIM];
    __shared__ float Rs[FDIM][FDIM];
    __shared__ float bs[FDIM];
    __shared__ float aRow[4][FDIM];
    __shared__ float xRow[4][FDIM];
    int tid = threadIdx.x;
    for (int i = tid; i < FDIM * FDIM; i += 256) {
        Ws[i >> 6][i & 63] = W[i];
        Rs[i >> 6][i & 63] = R[i];
    }
    if (tid < FDIM) bs[tid] = b[tid];
    int j = tid & 63, r = tid >> 6;
    int row = blockIdx.x * 4 + r;
    if (row < n) {
        float d = fmaxf(deg[row], 1.0f);
        aRow[r][j] = agg[(long long)row * FDIM + j] / d;
        xRow[r][j] = x[(long long)row * FDIM + j];
    }
    __syncthreads();
    if (row >= n) return;
    float acc = bs[j];
#pragma unroll
    for (int k = 0; k < FDIM; ++k)
        acc = fmaf(aRow[r][k], Ws[k][j], fmaf(xRow[r][k], Rs[k][j], acc));
    if (RELU) acc = fmaxf(acc, 0.0f);
    if (NORM) {
        float ss = acc * acc;
#pragma unroll
        for (int o = 32; o; o >>= 1) ss += __shfl_xor(ss, o, 64);
        acc *= 1.0f / fmaxf(sqrtf(ss), 1e-12f);
    }
    out[(long long)row * FDIM + j] = acc;
}

// ---------------------------------------------------------------------------

extern "C" void kernel_launch(void* const* d_in, const int* in_sizes, int n_in,
                              void* d_out, int out_size, void* d_ws, size_t ws_size,
                              hipStream_t stream)
{
    const float* x  = (const float*)d_in[0];
    const int*   e0 = (const int*)d_in[1];
    const int*   e1 = (const int*)d_in[2];
    const float* W1 = (const float*)d_in[3];
    const float* b1 = (const float*)d_in[4];
    const float* R1 = (const float*)d_in[5];
    const float* W2 = (const float*)d_in[6];
    const float* b2 = (const float*)d_in[7];
    const float* R2 = (const float*)d_in[8];
    float* out = (float*)d_out;

    const int N = in_sizes[0] / FDIM;     // 50000
    const int E = in_sizes[1] / 2;        // 1600000

    // CSR-path workspace: h[N*64] f32 | rowptr[N+1] | csridx[E] | cursor[N]
    const size_t need_csr =
        ((size_t)N * FDIM + (size_t)(N + 1) + (size_t)E + (size_t)N) * sizeof(float);

    const int eblocks = (E + 255) / 256;
    const int FUSED_BLOCKS = 1024;

    if (ws_size >= need_csr) {
        float* h      = (float*)d_ws;                 // 16B-aligned (rows are 256B)
        int*   rowptr = (int*)(h + (size_t)N * FDIM);
        int*   csridx = rowptr + (N + 1);
        int*   cursor = csridx + E;

        // ---- Layer 1: CSR over e0 (group by col), fused gather+dense+relu
        hipMemsetAsync(cursor, 0, (size_t)N * sizeof(int), stream);
        hist_kernel<<<eblocks, 256, 0, stream>>>(e0 + E, cursor, N, E);
        scan_kernel<<<1, 1024, 0, stream>>>(cursor, rowptr, N);
        hipMemsetAsync(cursor, 0, (size_t)N * sizeof(int), stream);
        fill_kernel<<<eblocks, 256, 0, stream>>>(e0, e0 + E, rowptr, cursor, csridx, N, E);
        fused_sage_kernel<true, false><<<FUSED_BLOCKS, 256, 0, stream>>>(
            rowptr, csridx, x, W1, b1, R1, h, N);

        // ---- Layer 2: CSR over e1 (buffers reused), fused gather+dense+norm
        hipMemsetAsync(cursor, 0, (size_t)N * sizeof(int), stream);
        hist_kernel<<<eblocks, 256, 0, stream>>>(e1 + E, cursor, N, E);
        scan_kernel<<<1, 1024, 0, stream>>>(cursor, rowptr, N);
        hipMemsetAsync(cursor, 0, (size_t)N * sizeof(int), stream);
        fill_kernel<<<eblocks, 256, 0, stream>>>(e1, e1 + E, rowptr, cursor, csridx, N, E);
        fused_sage_kernel<false, true><<<FUSED_BLOCKS, 256, 0, stream>>>(
            rowptr, csridx, h, W2, b2, R2, out, N);
    } else {
        // Fallback: atomic scatter path (round-3, verified)
        float* agg = (float*)d_ws;
        float* deg = agg + (long long)N * FDIM;
        float* h = out;
        const long long total = (long long)E * FDIM;
        const int sblocks = (int)((total + 255) / 256);
        const int dblocks = (N + 3) / 4;

        hipMemsetAsync(agg, 0, ((size_t)N * FDIM + N) * sizeof(float), stream);
        scatter_kernel<<<sblocks, 256, 0, stream>>>(x, e0, e0 + E, agg, deg, N, total);
        dense_kernel<true, false><<<dblocks, 256, 0, stream>>>(agg, deg, x, W1, b1, R1, h, N);

        hipMemsetAsync(agg, 0, ((size_t)N * FDIM + N) * sizeof(float), stream);
        scatter_kernel<<<sblocks, 256, 0, stream>>>(h, e1, e1 + E, agg, deg, N, total);
        dense_kernel<false, true><<<dblocks, 256, 0, stream>>>(agg, deg, h, W2, b2, R2, out, N);
    }
}

// Round 5
// 499.419 us; speedup vs baseline: 2.1005x; 1.3968x over previous
//
#include <hip/hip_runtime.h>
#include <hip/hip_bf16.h>

#define FDIM 64

// Bucketed CSR build parameters
#define NBLK_G 256        // P1/P3 grid
#define CHUNK_CAP 8192    // max edges per P1/P3 block (32 KB LDS stage)
#define BKT_SHIFT 7
#define BKT_NODES 128     // dest nodes per bucket
#define NB_MAX 512        // max buckets (N <= 65536)
#define STCAP 8192        // P4 LDS stage cap (edges)

__device__ __forceinline__ int clampi(int v, int n) { return min(max(v, 0), n - 1); }

// --------------------- P1: block-local bin + contiguous stage ---------------
__global__ __launch_bounds__(512) void p1_bin_stage(
    const int* __restrict__ rows, const int* __restrict__ cols,
    unsigned* __restrict__ pairs1, int* __restrict__ blockcnt,
    int n, int E, int nb, int chunk)
{
    __shared__ unsigned stage[CHUNK_CAP];
    __shared__ int hist[NB_MAX];
    __shared__ int curs[NB_MAX];
    int tid = threadIdx.x;
    int base = blockIdx.x * chunk;
    int cnt = E - base; if (cnt > chunk) cnt = chunk; if (cnt < 0) cnt = 0;
    for (int i = tid; i < NB_MAX; i += 512) hist[i] = 0;
    __syncthreads();
    for (int i = tid; i < cnt; i += 512) {
        int c = clampi(cols[base + i], n);
        atomicAdd(&hist[c >> BKT_SHIFT], 1);
    }
    __syncthreads();
    // per-(block,bucket) counts, coalesced
    for (int b = tid; b < nb; b += 512) blockcnt[blockIdx.x * nb + b] = hist[b];
    __syncthreads();
    // inclusive scan of hist[0..511]
    for (int off = 1; off < NB_MAX; off <<= 1) {
        int t = (tid >= off) ? hist[tid - off] : 0;
        __syncthreads();
        hist[tid] += t;
        __syncthreads();
    }
    curs[tid] = (tid == 0) ? 0 : hist[tid - 1];   // exclusive starts -> cursors
    __syncthreads();
    for (int i = tid; i < cnt; i += 512) {
        int c = clampi(cols[base + i], n);
        int r = clampi(rows[base + i], n);
        int p = atomicAdd(&curs[c >> BKT_SHIFT], 1);
        stage[p] = ((unsigned)r << 16) | (unsigned)c;
    }
    __syncthreads();
    for (int i = tid; i < cnt; i += 512) pairs1[base + i] = stage[i];
}

// --------------------- P2: counts -> global run starts + bucket bases -------
__global__ __launch_bounds__(512) void p2_offsets(
    int* __restrict__ blockcnt, int* __restrict__ bucketBase, int nb, int nblk)
{
    __shared__ int tot[NB_MAX];
    int tid = threadIdx.x;
    for (int b = tid; b < NB_MAX; b += 512) tot[b] = 0;
    __syncthreads();
    for (int b = tid; b < nb; b += 512) {
        int run = 0;
        for (int i = 0; i < nblk; ++i) {
            int idx = i * nb + b;
            int t = blockcnt[idx];
            blockcnt[idx] = run;      // within-bucket start (pre-base)
            run += t;
        }
        tot[b] = run;
    }
    __syncthreads();
    for (int off = 1; off < NB_MAX; off <<= 1) {
        int t = (tid >= off) ? tot[tid - off] : 0;
        __syncthreads();
        tot[tid] += t;
        __syncthreads();
    }
    if (tid < nb) bucketBase[tid] = (tid == 0) ? 0 : tot[tid - 1];
    if (tid == 0) bucketBase[nb] = tot[nb - 1];
    __syncthreads();
    for (int b = tid; b < nb; b += 512) {
        int basev = (b == 0) ? 0 : tot[b - 1];
        for (int i = 0; i < nblk; ++i) blockcnt[i * nb + b] += basev;
    }
}

// --------------------- P3: chunk (bucket-grouped) -> bucket-major -----------
__global__ __launch_bounds__(512) void p3_scatter(
    const unsigned* __restrict__ pairs1, const int* __restrict__ blockcnt,
    unsigned* __restrict__ pairs2, int E, int nb, int chunk)
{
    __shared__ int hist[NB_MAX];
    __shared__ int lstart[NB_MAX];
    __shared__ int gstart[NB_MAX];
    int tid = threadIdx.x;
    int base = blockIdx.x * chunk;
    int cnt = E - base; if (cnt > chunk) cnt = chunk; if (cnt < 0) cnt = 0;
    for (int i = tid; i < NB_MAX; i += 512) hist[i] = 0;
    __syncthreads();
    for (int b = tid; b < nb; b += 512) gstart[b] = blockcnt[blockIdx.x * nb + b];
    for (int i = tid; i < cnt; i += 512)
        atomicAdd(&hist[(pairs1[base + i] & 0xFFFFu) >> BKT_SHIFT], 1);
    __syncthreads();
    for (int off = 1; off < NB_MAX; off <<= 1) {
        int t = (tid >= off) ? hist[tid - off] : 0;
        __syncthreads();
        hist[tid] += t;
        __syncthreads();
    }
    lstart[tid] = (tid == 0) ? 0 : hist[tid - 1];
    __syncthreads();
    for (int i = tid; i < cnt; i += 512) {
        unsigned pk = pairs1[base + i];
        int b = (int)(pk & 0xFFFFu) >> BKT_SHIFT;
        pairs2[gstart[b] + (i - lstart[b])] = pk;   // runs -> coalesced
    }
}

// --------------------- P4: per-bucket fine CSR ------------------------------
__global__ __launch_bounds__(256) void p4_fine(
    const unsigned* __restrict__ pairs2, const int* __restrict__ bucketBase,
    int* __restrict__ rowptr, int* __restrict__ csridx, int n, int E, int nb)
{
    __shared__ unsigned st[STCAP];
    __shared__ int h[BKT_NODES];
    __shared__ int cur[BKT_NODES];
    int tid = threadIdx.x;
    int b = blockIdx.x;
    int beg = bucketBase[b], end = bucketBase[b + 1];
    int cnt = end - beg;
    for (int i = tid; i < BKT_NODES; i += 256) h[i] = 0;
    __syncthreads();
    bool fit = (cnt <= STCAP);
    if (fit) {
        for (int i = tid; i < cnt; i += 256) {
            unsigned pk = pairs2[beg + i];
            st[i] = pk;
            atomicAdd(&h[pk & (BKT_NODES - 1)], 1);
        }
    } else {
        for (int i = tid; i < cnt; i += 256)
            atomicAdd(&h[pairs2[beg + i] & (BKT_NODES - 1)], 1);
    }
    __syncthreads();
    for (int off = 1; off < BKT_NODES; off <<= 1) {
        int t = (tid >= off && tid < BKT_NODES) ? h[tid - off] : 0;
        __syncthreads();
        if (tid < BKT_NODES) h[tid] += t;
        __syncthreads();
    }
    if (tid < BKT_NODES) {
        int node = b * BKT_NODES + tid;
        int startl = (tid == 0) ? 0 : h[tid - 1];
        cur[tid] = startl;
        if (node < n) rowptr[node] = beg + startl;
    }
    __syncthreads();
    if (fit) {
        for (int i = tid; i < cnt; i += 256) {
            unsigned pk = st[i];
            int p = atomicAdd(&cur[pk & (BKT_NODES - 1)], 1);
            csridx[beg + p] = (int)(pk >> 16);
        }
    } else {
        // csridx buffer is disjoint from pairs2 -> safe two-sweep
        for (int i = tid; i < cnt; i += 256) {
            unsigned pk = pairs2[beg + i];
            int p = atomicAdd(&cur[pk & (BKT_NODES - 1)], 1);
            csridx[beg + p] = (int)(pk >> 16);
        }
    }
    if (b == nb - 1 && tid == 0) rowptr[n] = E;
}

// ------------- Fused gather(mean) + dense (+relu / +L2 norm) ----------------
template <bool RELU, bool NORM>
__global__ __launch_bounds__(256) void fused_sage_kernel(
    const int* __restrict__ rowptr, const int* __restrict__ csridx,
    const float* __restrict__ src,
    const float* __restrict__ W, const float* __restrict__ bvec,
    const float* __restrict__ R, float* __restrict__ out, int n)
{
    __shared__ float Ws[FDIM][FDIM];
    __shared__ float Rs[FDIM][FDIM];
    __shared__ float bs[FDIM];
    __shared__ float aRow[4][FDIM];
    __shared__ float xRow[4][FDIM];
    int tid = threadIdx.x;
    for (int i = tid; i < FDIM * FDIM; i += 256) {
        Ws[i >> 6][i & 63] = W[i];
        Rs[i >> 6][i & 63] = R[i];
    }
    if (tid < FDIM) bs[tid] = bvec[tid];
    __syncthreads();

    int lane = tid & 63, w = tid >> 6;
    int g = lane >> 4;
    int q = lane & 15;

    for (int node = blockIdx.x * 4 + w; node < n; node += gridDim.x * 4) {
        int beg = rowptr[node], end = rowptr[node + 1];
        float4 s4 = make_float4(0.f, 0.f, 0.f, 0.f);
        for (int base = beg; base < end; base += 64) {
            int cnt = end - base; if (cnt > 64) cnt = 64;
            int ei = base + lane;
            int myidx = (ei < end) ? csridx[ei] : 0;
            int steps = (cnt + 3) >> 2;
            for (int t = 0; t < steps; ++t) {
                int e = (t << 2) | g;
                int sidx = __shfl(myidx, e, 64);
                if (e < cnt) {
                    const float4* rp = (const float4*)(src + ((long long)sidx << 6));
                    float4 v = rp[q];
                    s4.x += v.x; s4.y += v.y; s4.z += v.z; s4.w += v.w;
                }
            }
        }
#pragma unroll
        for (int o = 16; o < 64; o <<= 1) {
            s4.x += __shfl_xor(s4.x, o, 64);
            s4.y += __shfl_xor(s4.y, o, 64);
            s4.z += __shfl_xor(s4.z, o, 64);
            s4.w += __shfl_xor(s4.w, o, 64);
        }
        float dinv = 1.0f / fmaxf((float)(end - beg), 1.0f);
        if (g == 0) {
            aRow[w][q * 4 + 0] = s4.x * dinv;
            aRow[w][q * 4 + 1] = s4.y * dinv;
            aRow[w][q * 4 + 2] = s4.z * dinv;
            aRow[w][q * 4 + 3] = s4.w * dinv;
        }
        xRow[w][lane] = src[((long long)node << 6) + lane];
        float acc = bs[lane];
#pragma unroll
        for (int k = 0; k < FDIM; ++k)
            acc = fmaf(aRow[w][k], Ws[k][lane], fmaf(xRow[w][k], Rs[k][lane], acc));
        if (RELU) acc = fmaxf(acc, 0.0f);
        if (NORM) {
            float ss = acc * acc;
#pragma unroll
            for (int o = 32; o; o >>= 1) ss += __shfl_xor(ss, o, 64);
            acc *= 1.0f / fmaxf(sqrtf(ss), 1e-12f);
        }
        out[((long long)node << 6) + lane] = acc;
    }
}

// ----------------- Round-4 CSR build (fallback, 19.6 MB ws) -----------------
__global__ __launch_bounds__(256) void hist_kernel(
    const int* __restrict__ cols, int* __restrict__ hist, int n, int E)
{
    int e = blockIdx.x * 256 + threadIdx.x;
    if (e >= E) return;
    atomicAdd(&hist[clampi(cols[e], n)], 1);
}

__global__ __launch_bounds__(1024) void scan_kernel(
    const int* __restrict__ hist, int* __restrict__ rowptr, int n)
{
    __shared__ int wsum[16];
    __shared__ int carry;
    int tid = threadIdx.x, lane = tid & 63, wid = tid >> 6;
    if (tid == 0) carry = 0;
    __syncthreads();
    for (int base = 0; base < n; base += 1024) {
        int i = base + tid;
        int v = (i < n) ? hist[i] : 0;
        int s = v;
#pragma unroll
        for (int o = 1; o < 64; o <<= 1) { int t = __shfl_up(s, o, 64); if (lane >= o) s += t; }
        if (lane == 63) wsum[wid] = s;
        __syncthreads();
        if (wid == 0) {
            int ws_ = (lane < 16) ? wsum[lane] : 0;
#pragma unroll
            for (int o = 1; o < 16; o <<= 1) { int t = __shfl_up(ws_, o, 64); if (lane >= o) ws_ += t; }
            if (lane < 16) wsum[lane] = ws_;
        }
        __syncthreads();
        int woff = (wid > 0) ? wsum[wid - 1] : 0;
        int excl = carry + woff + s - v;
        if (i < n) rowptr[i] = excl;
        int ctot = wsum[15];
        __syncthreads();
        if (tid == 0) carry += ctot;
        __syncthreads();
    }
    if (threadIdx.x == 0) rowptr[n] = carry;
}

__global__ __launch_bounds__(256) void fill_kernel(
    const int* __restrict__ rows, const int* __restrict__ cols,
    const int* __restrict__ rowptr, int* __restrict__ cursor,
    int* __restrict__ csridx, int n, int E)
{
    int e = blockIdx.x * 256 + threadIdx.x;
    if (e >= E) return;
    int c = clampi(cols[e], n);
    int p = atomicAdd(&cursor[c], 1);
    csridx[rowptr[c] + p] = clampi(rows[e], n);
}

// ----------------- Atomic scatter path (fallback, 13.0 MB ws) ---------------
__global__ __launch_bounds__(256) void scatter_kernel(
    const float* __restrict__ src, const int* __restrict__ rows, const int* __restrict__ cols,
    float* __restrict__ agg, float* __restrict__ deg, int n, long long total)
{
    long long gid = (long long)blockIdx.x * 256 + threadIdx.x;
    if (gid >= total) return;
    int e = (int)(gid >> 6);
    int f = (int)(gid & 63);
    int r = clampi(rows[e], n), c = clampi(cols[e], n);
    atomicAdd(&agg[(long long)c * FDIM + f], src[(long long)r * FDIM + f]);
    if (f == 0) atomicAdd(&deg[c], 1.0f);
}

template <bool RELU, bool NORM>
__global__ __launch_bounds__(256) void dense_kernel(
    const float* __restrict__ agg, const float* __restrict__ deg, const float* __restrict__ x,
    const float* __restrict__ W, const float* __restrict__ b,
    const float* __restrict__ R, float* __restrict__ out, int n)
{
    __shared__ float Ws[FDIM][FDIM];
    __shared__ float Rs[FDIM][FDIM];
    __shared__ float bs[FDIM];
    __shared__ float aRow[4][FDIM];
    __shared__ float xRow[4][FDIM];
    int tid = threadIdx.x;
    for (int i = tid; i < FDIM * FDIM; i += 256) {
        Ws[i >> 6][i & 63] = W[i];
        Rs[i >> 6][i & 63] = R[i];
    }
    if (tid < FDIM) bs[tid] = b[tid];
    int j = tid & 63, r = tid >> 6;
    int row = blockIdx.x * 4 + r;
    if (row < n) {
        float d = fmaxf(deg[row], 1.0f);
        aRow[r][j] = agg[(long long)row * FDIM + j] / d;
        xRow[r][j] = x[(long long)row * FDIM + j];
    }
    __syncthreads();
    if (row >= n) return;
    float acc = bs[j];
#pragma unroll
    for (int k = 0; k < FDIM; ++k)
        acc = fmaf(aRow[r][k], Ws[k][j], fmaf(xRow[r][k], Rs[k][j], acc));
    if (RELU) acc = fmaxf(acc, 0.0f);
    if (NORM) {
        float ss = acc * acc;
#pragma unroll
        for (int o = 32; o; o >>= 1) ss += __shfl_xor(ss, o, 64);
        acc *= 1.0f / fmaxf(sqrtf(ss), 1e-12f);
    }
    out[(long long)row * FDIM + j] = acc;
}

// ---------------------------------------------------------------------------
extern "C" void kernel_launch(void* const* d_in, const int* in_sizes, int n_in,
                              void* d_out, int out_size, void* d_ws, size_t ws_size,
                              hipStream_t stream)
{
    const float* x  = (const float*)d_in[0];
    const int*   e0 = (const int*)d_in[1];
    const int*   e1 = (const int*)d_in[2];
    const float* W1 = (const float*)d_in[3];
    const float* b1 = (const float*)d_in[4];
    const float* R1 = (const float*)d_in[5];
    const float* W2 = (const float*)d_in[6];
    const float* b2 = (const float*)d_in[7];
    const float* R2 = (const float*)d_in[8];
    float* out = (float*)d_out;

    const int N = in_sizes[0] / FDIM;     // 50000
    const int E = in_sizes[1] / 2;        // 1600000

    const int nb = (N + BKT_NODES - 1) >> BKT_SHIFT;
    const int chunk = (E + NBLK_G - 1) / NBLK_G;
    const int FUSED_BLOCKS = 1024;

    // Path 1 (bucketed build) workspace:
    // h[N*64] f32 | pairs1[E] u32 (later csridx) | pairs2[E] u32 |
    // blockcnt[NBLK_G*nb] | bucketBase[nb+1] | rowptr[N+1]
    const size_t need1 = ((size_t)N * FDIM + 2 * (size_t)E +
                          (size_t)NBLK_G * nb + (nb + 1) + (N + 1)) * 4;
    const size_t need2 = ((size_t)N * FDIM + (size_t)(N + 1) + (size_t)E + (size_t)N) * 4;

    const bool ok1 = (ws_size >= need1) && (N <= 65536) && (chunk <= CHUNK_CAP) && (nb <= NB_MAX);

    if (ok1) {
        float*    h        = (float*)d_ws;
        unsigned* pairs1   = (unsigned*)(h + (size_t)N * FDIM);
        unsigned* pairs2   = pairs1 + E;
        int*      blockcnt = (int*)(pairs2 + E);
        int*      bucketBase = blockcnt + (size_t)NBLK_G * nb;
        int*      rowptr   = bucketBase + (nb + 1);
        int*      csridx   = (int*)pairs1;   // pairs1 dead after P3

        // ---- Layer 1 ----
        p1_bin_stage<<<NBLK_G, 512, 0, stream>>>(e0, e0 + E, pairs1, blockcnt, N, E, nb, chunk);
        p2_offsets<<<1, 512, 0, stream>>>(blockcnt, bucketBase, nb, NBLK_G);
        p3_scatter<<<NBLK_G, 512, 0, stream>>>(pairs1, blockcnt, pairs2, E, nb, chunk);
        p4_fine<<<nb, 256, 0, stream>>>(pairs2, bucketBase, rowptr, csridx, N, E, nb);
        fused_sage_kernel<true, false><<<FUSED_BLOCKS, 256, 0, stream>>>(
            rowptr, csridx, x, W1, b1, R1, h, N);

        // ---- Layer 2 ----
        p1_bin_stage<<<NBLK_G, 512, 0, stream>>>(e1, e1 + E, pairs1, blockcnt, N, E, nb, chunk);
        p2_offsets<<<1, 512, 0, stream>>>(blockcnt, bucketBase, nb, NBLK_G);
        p3_scatter<<<NBLK_G, 512, 0, stream>>>(pairs1, blockcnt, pairs2, E, nb, chunk);
        p4_fine<<<nb, 256, 0, stream>>>(pairs2, bucketBase, rowptr, csridx, N, E, nb);
        fused_sage_kernel<false, true><<<FUSED_BLOCKS, 256, 0, stream>>>(
            rowptr, csridx, h, W2, b2, R2, out, N);
    } else if (ws_size >= need2) {
        float* h      = (float*)d_ws;
        int*   rowptr = (int*)(h + (size_t)N * FDIM);
        int*   csridx = rowptr + (N + 1);
        int*   cursor = csridx + E;
        const int eblocks = (E + 255) / 256;

        hipMemsetAsync(cursor, 0, (size_t)N * sizeof(int), stream);
        hist_kernel<<<eblocks, 256, 0, stream>>>(e0 + E, cursor, N, E);
        scan_kernel<<<1, 1024, 0, stream>>>(cursor, rowptr, N);
        hipMemsetAsync(cursor, 0, (size_t)N * sizeof(int), stream);
        fill_kernel<<<eblocks, 256, 0, stream>>>(e0, e0 + E, rowptr, cursor, csridx, N, E);
        fused_sage_kernel<true, false><<<FUSED_BLOCKS, 256, 0, stream>>>(
            rowptr, csridx, x, W1, b1, R1, h, N);

        hipMemsetAsync(cursor, 0, (size_t)N * sizeof(int), stream);
        hist_kernel<<<eblocks, 256, 0, stream>>>(e1 + E, cursor, N, E);
        scan_kernel<<<1, 1024, 0, stream>>>(cursor, rowptr, N);
        hipMemsetAsync(cursor, 0, (size_t)N * sizeof(int), stream);
        fill_kernel<<<eblocks, 256, 0, stream>>>(e1, e1 + E, rowptr, cursor, csridx, N, E);
        fused_sage_kernel<false, true><<<FUSED_BLOCKS, 256, 0, stream>>>(
            rowptr, csridx, h, W2, b2, R2, out, N);
    } else {
        float* agg = (float*)d_ws;
        float* deg = agg + (long long)N * FDIM;
        float* h = out;
        const long long total = (long long)E * FDIM;
        const int sblocks = (int)((total + 255) / 256);
        const int dblocks = (N + 3) / 4;

        hipMemsetAsync(agg, 0, ((size_t)N * FDIM + N) * sizeof(float), stream);
        scatter_kernel<<<sblocks, 256, 0, stream>>>(x, e0, e0 + E, agg, deg, N, total);
        dense_kernel<true, false><<<dblocks, 256, 0, stream>>>(agg, deg, x, W1, b1, R1, h, N);

        hipMemsetAsync(agg, 0, ((size_t)N * FDIM + N) * sizeof(float), stream);
        scatter_kernel<<<sblocks, 256, 0, stream>>>(h, e1, e1 + E, agg, deg, N, total);
        dense_kernel<false, true><<<dblocks, 256, 0, stream>>>(agg, deg, h, W2, b2, R2, out, N);
    }
}

// Round 6
// 329.815 us; speedup vs baseline: 3.1807x; 1.5142x over previous
//
#include <hip/hip_runtime.h>
#include <hip/hip_bf16.h>

#define FDIM 64

// Bucketed CSR build parameters
#define NBLK_G 256        // P1/P3 grid
#define CHUNK_CAP 8192    // max edges per P1/P3 block (32 KB LDS stage)
#define BKT_SHIFT 7
#define BKT_NODES 128     // dest nodes per bucket
#define NB_MAX 512        // max buckets (N <= 65536)
#define STCAP 8192        // P4 LDS stage cap (edges)

__device__ __forceinline__ int clampi(int v, int n) { return min(max(v, 0), n - 1); }

// --------------------- P1: block-local bin + contiguous stage ---------------
__global__ __launch_bounds__(512) void p1_bin_stage(
    const int* __restrict__ rows, const int* __restrict__ cols,
    unsigned* __restrict__ pairs1, int* __restrict__ blockcnt,
    int n, int E, int nb, int chunk)
{
    __shared__ unsigned stage[CHUNK_CAP];
    __shared__ int hist[NB_MAX];
    __shared__ int curs[NB_MAX];
    int tid = threadIdx.x;
    int base = blockIdx.x * chunk;
    int cnt = E - base; if (cnt > chunk) cnt = chunk; if (cnt < 0) cnt = 0;
    for (int i = tid; i < NB_MAX; i += 512) hist[i] = 0;
    __syncthreads();
    for (int i = tid; i < cnt; i += 512) {
        int c = clampi(cols[base + i], n);
        atomicAdd(&hist[c >> BKT_SHIFT], 1);
    }
    __syncthreads();
    for (int b = tid; b < nb; b += 512) blockcnt[blockIdx.x * nb + b] = hist[b];
    __syncthreads();
    for (int off = 1; off < NB_MAX; off <<= 1) {
        int t = (tid >= off) ? hist[tid - off] : 0;
        __syncthreads();
        hist[tid] += t;
        __syncthreads();
    }
    curs[tid] = (tid == 0) ? 0 : hist[tid - 1];
    __syncthreads();
    for (int i = tid; i < cnt; i += 512) {
        int c = clampi(cols[base + i], n);
        int r = clampi(rows[base + i], n);
        int p = atomicAdd(&curs[c >> BKT_SHIFT], 1);
        stage[p] = ((unsigned)r << 16) | (unsigned)c;
    }
    __syncthreads();
    for (int i = tid; i < cnt; i += 512) pairs1[base + i] = stage[i];
}

// --------------------- P2a: per-bucket column scan (1 wave / bucket) --------
__global__ __launch_bounds__(64) void p2a_colscan(
    int* __restrict__ blockcnt, int* __restrict__ bucketTot, int nb, int nblk)
{
    int b = blockIdx.x;
    int lane = threadIdx.x;
    int chunk = (nblk + 63) >> 6;      // nblk=256 -> 4
    int beg = lane * chunk;
    int endi = min(beg + chunk, nblk);
    int vals[8];                        // chunk <= 8 (nblk <= 512)
    int s = 0;
    for (int i = beg, j = 0; i < endi; ++i, ++j) {
        vals[j] = blockcnt[(size_t)i * nb + b];
        s += vals[j];
    }
    int incl = s;
#pragma unroll
    for (int o = 1; o < 64; o <<= 1) {
        int t = __shfl_up(incl, o, 64);
        if (lane >= o) incl += t;
    }
    int run = incl - s;                 // exclusive start for this lane's chunk
    for (int i = beg, j = 0; i < endi; ++i, ++j) {
        int t = vals[j];
        blockcnt[(size_t)i * nb + b] = run;
        run += t;
    }
    if (lane == 63) bucketTot[b] = incl;
}

// --------------------- P2b: bucket totals -> bucket bases -------------------
__global__ __launch_bounds__(512) void p2b_basescan(
    const int* __restrict__ bucketTot, int* __restrict__ bucketBase, int nb)
{
    __shared__ int tot[NB_MAX];
    int tid = threadIdx.x;
    tot[tid] = (tid < nb) ? bucketTot[tid] : 0;
    __syncthreads();
    for (int off = 1; off < NB_MAX; off <<= 1) {
        int t = (tid >= off) ? tot[tid - off] : 0;
        __syncthreads();
        tot[tid] += t;
        __syncthreads();
    }
    if (tid < nb) bucketBase[tid] = (tid == 0) ? 0 : tot[tid - 1];
    if (tid == 0) bucketBase[nb] = tot[nb - 1];
}

// --------------------- P2c: add bucket base to every run start --------------
__global__ __launch_bounds__(256) void p2c_addbase(
    int* __restrict__ blockcnt, const int* __restrict__ bucketBase, int nb, int total)
{
    int i = blockIdx.x * 256 + threadIdx.x;
    if (i >= total) return;
    blockcnt[i] += bucketBase[i % nb];
}

// --------------------- P3: chunk (bucket-grouped) -> bucket-major -----------
__global__ __launch_bounds__(512) void p3_scatter(
    const unsigned* __restrict__ pairs1, const int* __restrict__ blockcnt,
    unsigned* __restrict__ pairs2, int E, int nb, int chunk)
{
    __shared__ int hist[NB_MAX];
    __shared__ int lstart[NB_MAX];
    __shared__ int gstart[NB_MAX];
    int tid = threadIdx.x;
    int base = blockIdx.x * chunk;
    int cnt = E - base; if (cnt > chunk) cnt = chunk; if (cnt < 0) cnt = 0;
    for (int i = tid; i < NB_MAX; i += 512) hist[i] = 0;
    __syncthreads();
    for (int b = tid; b < nb; b += 512) gstart[b] = blockcnt[blockIdx.x * nb + b];
    for (int i = tid; i < cnt; i += 512)
        atomicAdd(&hist[(pairs1[base + i] & 0xFFFFu) >> BKT_SHIFT], 1);
    __syncthreads();
    for (int off = 1; off < NB_MAX; off <<= 1) {
        int t = (tid >= off) ? hist[tid - off] : 0;
        __syncthreads();
        hist[tid] += t;
        __syncthreads();
    }
    lstart[tid] = (tid == 0) ? 0 : hist[tid - 1];
    __syncthreads();
    for (int i = tid; i < cnt; i += 512) {
        unsigned pk = pairs1[base + i];
        int b = (int)(pk & 0xFFFFu) >> BKT_SHIFT;
        pairs2[gstart[b] + (i - lstart[b])] = pk;
    }
}

// --------------------- P4: per-bucket fine CSR ------------------------------
__global__ __launch_bounds__(256) void p4_fine(
    const unsigned* __restrict__ pairs2, const int* __restrict__ bucketBase,
    int* __restrict__ rowptr, int* __restrict__ csridx, int n, int E, int nb)
{
    __shared__ unsigned st[STCAP];
    __shared__ int h[BKT_NODES];
    __shared__ int cur[BKT_NODES];
    int tid = threadIdx.x;
    int b = blockIdx.x;
    int beg = bucketBase[b], end = bucketBase[b + 1];
    int cnt = end - beg;
    for (int i = tid; i < BKT_NODES; i += 256) h[i] = 0;
    __syncthreads();
    bool fit = (cnt <= STCAP);
    if (fit) {
        for (int i = tid; i < cnt; i += 256) {
            unsigned pk = pairs2[beg + i];
            st[i] = pk;
            atomicAdd(&h[pk & (BKT_NODES - 1)], 1);
        }
    } else {
        for (int i = tid; i < cnt; i += 256)
            atomicAdd(&h[pairs2[beg + i] & (BKT_NODES - 1)], 1);
    }
    __syncthreads();
    for (int off = 1; off < BKT_NODES; off <<= 1) {
        int t = (tid >= off && tid < BKT_NODES) ? h[tid - off] : 0;
        __syncthreads();
        if (tid < BKT_NODES) h[tid] += t;
        __syncthreads();
    }
    if (tid < BKT_NODES) {
        int node = b * BKT_NODES + tid;
        int startl = (tid == 0) ? 0 : h[tid - 1];
        cur[tid] = startl;
        if (node < n) rowptr[node] = beg + startl;
    }
    __syncthreads();
    if (fit) {
        for (int i = tid; i < cnt; i += 256) {
            unsigned pk = st[i];
            int p = atomicAdd(&cur[pk & (BKT_NODES - 1)], 1);
            csridx[beg + p] = (int)(pk >> 16);
        }
    } else {
        for (int i = tid; i < cnt; i += 256) {
            unsigned pk = pairs2[beg + i];
            int p = atomicAdd(&cur[pk & (BKT_NODES - 1)], 1);
            csridx[beg + p] = (int)(pk >> 16);
        }
    }
    if (b == nb - 1 && tid == 0) rowptr[n] = E;
}

// ------------- Fused gather(mean) + dense (+relu / +L2 norm) ----------------
template <bool RELU, bool NORM>
__global__ __launch_bounds__(256) void fused_sage_kernel(
    const int* __restrict__ rowptr, const int* __restrict__ csridx,
    const float* __restrict__ src,
    const float* __restrict__ W, const float* __restrict__ bvec,
    const float* __restrict__ R, float* __restrict__ out, int n)
{
    __shared__ float Ws[FDIM][FDIM];
    __shared__ float Rs[FDIM][FDIM];
    __shared__ float bs[FDIM];
    __shared__ float aRow[4][FDIM];
    __shared__ float xRow[4][FDIM];
    int tid = threadIdx.x;
    for (int i = tid; i < FDIM * FDIM; i += 256) {
        Ws[i >> 6][i & 63] = W[i];
        Rs[i >> 6][i & 63] = R[i];
    }
    if (tid < FDIM) bs[tid] = bvec[tid];
    __syncthreads();

    int lane = tid & 63, w = tid >> 6;
    int g = lane >> 4;
    int q = lane & 15;

    for (int node = blockIdx.x * 4 + w; node < n; node += gridDim.x * 4) {
        int beg = rowptr[node], end = rowptr[node + 1];
        float4 s4 = make_float4(0.f, 0.f, 0.f, 0.f);
        for (int base = beg; base < end; base += 64) {
            int cnt = end - base; if (cnt > 64) cnt = 64;
            int ei = base + lane;
            int myidx = (ei < end) ? csridx[ei] : 0;
            int steps = (cnt + 3) >> 2;
            for (int t = 0; t < steps; ++t) {
                int e = (t << 2) | g;
                int sidx = __shfl(myidx, e, 64);
                if (e < cnt) {
                    const float4* rp = (const float4*)(src + ((long long)sidx << 6));
                    float4 v = rp[q];
                    s4.x += v.x; s4.y += v.y; s4.z += v.z; s4.w += v.w;
                }
            }
        }
#pragma unroll
        for (int o = 16; o < 64; o <<= 1) {
            s4.x += __shfl_xor(s4.x, o, 64);
            s4.y += __shfl_xor(s4.y, o, 64);
            s4.z += __shfl_xor(s4.z, o, 64);
            s4.w += __shfl_xor(s4.w, o, 64);
        }
        float dinv = 1.0f / fmaxf((float)(end - beg), 1.0f);
        if (g == 0) {
            aRow[w][q * 4 + 0] = s4.x * dinv;
            aRow[w][q * 4 + 1] = s4.y * dinv;
            aRow[w][q * 4 + 2] = s4.z * dinv;
            aRow[w][q * 4 + 3] = s4.w * dinv;
        }
        xRow[w][lane] = src[((long long)node << 6) + lane];
        float acc = bs[lane];
#pragma unroll
        for (int k = 0; k < FDIM; ++k)
            acc = fmaf(aRow[w][k], Ws[k][lane], fmaf(xRow[w][k], Rs[k][lane], acc));
        if (RELU) acc = fmaxf(acc, 0.0f);
        if (NORM) {
            float ss = acc * acc;
#pragma unroll
            for (int o = 32; o; o >>= 1) ss += __shfl_xor(ss, o, 64);
            acc *= 1.0f / fmaxf(sqrtf(ss), 1e-12f);
        }
        out[((long long)node << 6) + lane] = acc;
    }
}

// ----------------- Atomic scatter path (fallback, 13.0 MB ws) ---------------
__global__ __launch_bounds__(256) void scatter_kernel(
    const float* __restrict__ src, const int* __restrict__ rows, const int* __restrict__ cols,
    float* __restrict__ agg, float* __restrict__ deg, int n, long long total)
{
    long long gid = (long long)blockIdx.x * 256 + threadIdx.x;
    if (gid >= total) return;
    int e = (int)(gid >> 6);
    int f = (int)(gid & 63);
    int r = clampi(rows[e], n), c = clampi(cols[e], n);
    atomicAdd(&agg[(long long)c * FDIM + f], src[(long long)r * FDIM + f]);
    if (f == 0) atomicAdd(&deg[c], 1.0f);
}

template <bool RELU, bool NORM>
__global__ __launch_bounds__(256) void dense_kernel(
    const float* __restrict__ agg, const float* __restrict__ deg, const float* __restrict__ x,
    const float* __restrict__ W, const float* __restrict__ b,
    const float* __restrict__ R, float* __restrict__ out, int n)
{
    __shared__ float Ws[FDIM][FDIM];
    __shared__ float Rs[FDIM][FDIM];
    __shared__ float bs[FDIM];
    __shared__ float aRow[4][FDIM];
    __shared__ float xRow[4][FDIM];
    int tid = threadIdx.x;
    for (int i = tid; i < FDIM * FDIM; i += 256) {
        Ws[i >> 6][i & 63] = W[i];
        Rs[i >> 6][i & 63] = R[i];
    }
    if (tid < FDIM) bs[tid] = b[tid];
    int j = tid & 63, r = tid >> 6;
    int row = blockIdx.x * 4 + r;
    if (row < n) {
        float d = fmaxf(deg[row], 1.0f);
        aRow[r][j] = agg[(long long)row * FDIM + j] / d;
        xRow[r][j] = x[(long long)row * FDIM + j];
    }
    __syncthreads();
    if (row >= n) return;
    float acc = bs[j];
#pragma unroll
    for (int k = 0; k < FDIM; ++k)
        acc = fmaf(aRow[r][k], Ws[k][j], fmaf(xRow[r][k], Rs[k][j], acc));
    if (RELU) acc = fmaxf(acc, 0.0f);
    if (NORM) {
        float ss = acc * acc;
#pragma unroll
        for (int o = 32; o; o >>= 1) ss += __shfl_xor(ss, o, 64);
        acc *= 1.0f / fmaxf(sqrtf(ss), 1e-12f);
    }
    out[(long long)row * FDIM + j] = acc;
}

// ---------------------------------------------------------------------------
extern "C" void kernel_launch(void* const* d_in, const int* in_sizes, int n_in,
                              void* d_out, int out_size, void* d_ws, size_t ws_size,
                              hipStream_t stream)
{
    const float* x  = (const float*)d_in[0];
    const int*   e0 = (const int*)d_in[1];
    const int*   e1 = (const int*)d_in[2];
    const float* W1 = (const float*)d_in[3];
    const float* b1 = (const float*)d_in[4];
    const float* R1 = (const float*)d_in[5];
    const float* W2 = (const float*)d_in[6];
    const float* b2 = (const float*)d_in[7];
    const float* R2 = (const float*)d_in[8];
    float* out = (float*)d_out;

    const int N = in_sizes[0] / FDIM;     // 50000
    const int E = in_sizes[1] / 2;        // 1600000

    const int nb = (N + BKT_NODES - 1) >> BKT_SHIFT;
    const int chunk = (E + NBLK_G - 1) / NBLK_G;
    const int FUSED_BLOCKS = 1024;
    const int cnt_total = NBLK_G * nb;

    // Path 1 workspace: h[N*64] f32 | pairs1[E] u32 (later csridx) | pairs2[E] u32 |
    // blockcnt[NBLK_G*nb] | bucketBase[nb+1] | bucketTot[nb] | rowptr[N+1]
    const size_t need1 = ((size_t)N * FDIM + 2 * (size_t)E +
                          (size_t)cnt_total + (nb + 1) + nb + (N + 1)) * 4;
    const size_t need_fb = ((size_t)N * FDIM + (size_t)N) * 4;

    const bool ok1 = (ws_size >= need1) && (N <= 65536) && (chunk <= CHUNK_CAP) && (nb <= NB_MAX);

    if (ok1) {
        float*    h          = (float*)d_ws;
        unsigned* pairs1     = (unsigned*)(h + (size_t)N * FDIM);
        unsigned* pairs2     = pairs1 + E;
        int*      blockcnt   = (int*)(pairs2 + E);
        int*      bucketBase = blockcnt + (size_t)cnt_total;
        int*      bucketTot  = bucketBase + (nb + 1);
        int*      rowptr     = bucketTot + nb;
        int*      csridx     = (int*)pairs1;   // pairs1 dead after P3

        // ---- Layer 1 ----
        p1_bin_stage<<<NBLK_G, 512, 0, stream>>>(e0, e0 + E, pairs1, blockcnt, N, E, nb, chunk);
        p2a_colscan<<<nb, 64, 0, stream>>>(blockcnt, bucketTot, nb, NBLK_G);
        p2b_basescan<<<1, 512, 0, stream>>>(bucketTot, bucketBase, nb);
        p2c_addbase<<<(cnt_total + 255) / 256, 256, 0, stream>>>(blockcnt, bucketBase, nb, cnt_total);
        p3_scatter<<<NBLK_G, 512, 0, stream>>>(pairs1, blockcnt, pairs2, E, nb, chunk);
        p4_fine<<<nb, 256, 0, stream>>>(pairs2, bucketBase, rowptr, csridx, N, E, nb);
        fused_sage_kernel<true, false><<<FUSED_BLOCKS, 256, 0, stream>>>(
            rowptr, csridx, x, W1, b1, R1, h, N);

        // ---- Layer 2 ----
        p1_bin_stage<<<NBLK_G, 512, 0, stream>>>(e1, e1 + E, pairs1, blockcnt, N, E, nb, chunk);
        p2a_colscan<<<nb, 64, 0, stream>>>(blockcnt, bucketTot, nb, NBLK_G);
        p2b_basescan<<<1, 512, 0, stream>>>(bucketTot, bucketBase, nb);
        p2c_addbase<<<(cnt_total + 255) / 256, 256, 0, stream>>>(blockcnt, bucketBase, nb, cnt_total);
        p3_scatter<<<NBLK_G, 512, 0, stream>>>(pairs1, blockcnt, pairs2, E, nb, chunk);
        p4_fine<<<nb, 256, 0, stream>>>(pairs2, bucketBase, rowptr, csridx, N, E, nb);
        fused_sage_kernel<false, true><<<FUSED_BLOCKS, 256, 0, stream>>>(
            rowptr, csridx, h, W2, b2, R2, out, N);
    } else {
        // Fallback: atomic scatter path (round-3, verified)
        float* agg = (float*)d_ws;
        float* deg = agg + (long long)N * FDIM;
        float* h = out;
        const long long total = (long long)E * FDIM;
        const int sblocks = (int)((total + 255) / 256);
        const int dblocks = (N + 3) / 4;
        (void)need_fb;

        hipMemsetAsync(agg, 0, ((size_t)N * FDIM + N) * sizeof(float), stream);
        scatter_kernel<<<sblocks, 256, 0, stream>>>(x, e0, e0 + E, agg, deg, N, total);
        dense_kernel<true, false><<<dblocks, 256, 0, stream>>>(agg, deg, x, W1, b1, R1, h, N);

        hipMemsetAsync(agg, 0, ((size_t)N * FDIM + N) * sizeof(float), stream);
        scatter_kernel<<<sblocks, 256, 0, stream>>>(h, e1, e1 + E, agg, deg, N, total);
        dense_kernel<false, true><<<dblocks, 256, 0, stream>>>(agg, deg, h, W2, b2, R2, out, N);
    }
}

// Round 7
// 329.266 us; speedup vs baseline: 3.1860x; 1.0017x over previous
//
#include <hip/hip_runtime.h>
#include <hip/hip_bf16.h>
#include <hip/hip_fp16.h>

#define FDIM 64

// Bucketed CSR build parameters
#define NBLK_G 256        // chunk-grid for p1a/p3
#define CHUNK_CAP 8192    // max edges per chunk block (32 KB LDS stage)
#define BKT_SHIFT 7
#define BKT_NODES 128     // dest nodes per bucket
#define NB_MAX 512        // max buckets (N <= 65536)
#define STCAP 8192        // P4 LDS stage cap (edges)

__device__ __forceinline__ int clampi(int v, int n) { return min(max(v, 0), n - 1); }

// --------------------- convert fp32 -> fp16 shadow table --------------------
__global__ __launch_bounds__(256) void convert_half(
    const float* __restrict__ in32, __half* __restrict__ out16, int n)
{
    int i = blockIdx.x * 256 + threadIdx.x;
    if (i < n) out16[i] = __float2half(in32[i]);
}

// --------------------- P1a: per-chunk bucket histogram ----------------------
__global__ __launch_bounds__(256) void p1a_hist(
    const int* __restrict__ cols, int* __restrict__ blockcnt,
    int n, int E, int nb, int chunk)
{
    __shared__ int hist[NB_MAX];
    int tid = threadIdx.x;
    int base = blockIdx.x * chunk;
    int cnt = E - base; if (cnt > chunk) cnt = chunk; if (cnt < 0) cnt = 0;
    for (int i = tid; i < NB_MAX; i += 256) hist[i] = 0;
    __syncthreads();
    for (int i = tid; i < cnt; i += 256)
        atomicAdd(&hist[clampi(cols[base + i], n) >> BKT_SHIFT], 1);
    __syncthreads();
    for (int b = tid; b < nb; b += 256) blockcnt[blockIdx.x * nb + b] = hist[b];
}

// --------------------- P2a: per-bucket column scan (1 wave / bucket) --------
__global__ __launch_bounds__(64) void p2a_colscan(
    int* __restrict__ blockcnt, int* __restrict__ bucketTot, int nb, int nblk)
{
    int b = blockIdx.x;
    int lane = threadIdx.x;
    int chunk = (nblk + 63) >> 6;
    int beg = lane * chunk;
    int endi = min(beg + chunk, nblk);
    int vals[8];
    int s = 0;
    for (int i = beg, j = 0; i < endi; ++i, ++j) {
        vals[j] = blockcnt[(size_t)i * nb + b];
        s += vals[j];
    }
    int incl = s;
#pragma unroll
    for (int o = 1; o < 64; o <<= 1) {
        int t = __shfl_up(incl, o, 64);
        if (lane >= o) incl += t;
    }
    int run = incl - s;
    for (int i = beg, j = 0; i < endi; ++i, ++j) {
        int t = vals[j];
        blockcnt[(size_t)i * nb + b] = run;   // within-bucket exclusive start
        run += t;
    }
    if (lane == 63) bucketTot[b] = incl;
}

// --------------------- P2b: bucket totals -> bucket bases -------------------
__global__ __launch_bounds__(512) void p2b_basescan(
    const int* __restrict__ bucketTot, int* __restrict__ bucketBase, int nb)
{
    __shared__ int tot[NB_MAX];
    int tid = threadIdx.x;
    tot[tid] = (tid < nb) ? bucketTot[tid] : 0;
    __syncthreads();
    for (int off = 1; off < NB_MAX; off <<= 1) {
        int t = (tid >= off) ? tot[tid - off] : 0;
        __syncthreads();
        tot[tid] += t;
        __syncthreads();
    }
    if (tid < nb) bucketBase[tid] = (tid == 0) ? 0 : tot[tid - 1];
    if (tid == 0) bucketBase[nb] = tot[nb - 1];
}

// ---------- P3: re-read chunk, LDS-bin by bucket, write bucket-major --------
__global__ __launch_bounds__(512) void p3_binscatter(
    const int* __restrict__ rows, const int* __restrict__ cols,
    const int* __restrict__ blockcnt, const int* __restrict__ bucketBase,
    unsigned* __restrict__ pairs2, int n, int E, int nb, int chunk)
{
    __shared__ unsigned stage[CHUNK_CAP];
    __shared__ int hist[NB_MAX];
    __shared__ int curs[NB_MAX];
    __shared__ int lstart[NB_MAX];
    __shared__ int gbase[NB_MAX];
    int tid = threadIdx.x;
    int base = blockIdx.x * chunk;
    int cnt = E - base; if (cnt > chunk) cnt = chunk; if (cnt < 0) cnt = 0;
    for (int i = tid; i < NB_MAX; i += 512) hist[i] = 0;
    __syncthreads();
    for (int b = tid; b < nb; b += 512)
        gbase[b] = bucketBase[b] + blockcnt[blockIdx.x * nb + b];
    for (int i = tid; i < cnt; i += 512)
        atomicAdd(&hist[clampi(cols[base + i], n) >> BKT_SHIFT], 1);
    __syncthreads();
    for (int off = 1; off < NB_MAX; off <<= 1) {
        int t = (tid >= off) ? hist[tid - off] : 0;
        __syncthreads();
        hist[tid] += t;
        __syncthreads();
    }
    lstart[tid] = (tid == 0) ? 0 : hist[tid - 1];
    curs[tid] = lstart[tid];
    __syncthreads();
    for (int i = tid; i < cnt; i += 512) {
        int c = clampi(cols[base + i], n);
        int r = clampi(rows[base + i], n);
        int p = atomicAdd(&curs[c >> BKT_SHIFT], 1);
        stage[p] = ((unsigned)r << 16) | (unsigned)c;
    }
    __syncthreads();
    for (int i = tid; i < cnt; i += 512) {
        unsigned pk = stage[i];
        int b = (int)(pk & 0xFFFFu) >> BKT_SHIFT;
        pairs2[gbase[b] + (i - lstart[b])] = pk;   // contiguous runs
    }
}

// --------------------- P4: per-bucket fine CSR (ushort idx) -----------------
__global__ __launch_bounds__(256) void p4_fine(
    const unsigned* __restrict__ pairs2, const int* __restrict__ bucketBase,
    int* __restrict__ rowptr, unsigned short* __restrict__ csridx,
    int n, int E, int nb)
{
    __shared__ unsigned st[STCAP];
    __shared__ int h[BKT_NODES];
    __shared__ int cur[BKT_NODES];
    int tid = threadIdx.x;
    int b = blockIdx.x;
    int beg = bucketBase[b], end = bucketBase[b + 1];
    int cnt = end - beg;
    for (int i = tid; i < BKT_NODES; i += 256) h[i] = 0;
    __syncthreads();
    bool fit = (cnt <= STCAP);
    if (fit) {
        for (int i = tid; i < cnt; i += 256) {
            unsigned pk = pairs2[beg + i];
            st[i] = pk;
            atomicAdd(&h[pk & (BKT_NODES - 1)], 1);
        }
    } else {
        for (int i = tid; i < cnt; i += 256)
            atomicAdd(&h[pairs2[beg + i] & (BKT_NODES - 1)], 1);
    }
    __syncthreads();
    for (int off = 1; off < BKT_NODES; off <<= 1) {
        int t = (tid >= off && tid < BKT_NODES) ? h[tid - off] : 0;
        __syncthreads();
        if (tid < BKT_NODES) h[tid] += t;
        __syncthreads();
    }
    if (tid < BKT_NODES) {
        int node = b * BKT_NODES + tid;
        int startl = (tid == 0) ? 0 : h[tid - 1];
        cur[tid] = startl;
        if (node < n) rowptr[node] = beg + startl;
    }
    __syncthreads();
    if (fit) {
        for (int i = tid; i < cnt; i += 256) {
            unsigned pk = st[i];
            int p = atomicAdd(&cur[pk & (BKT_NODES - 1)], 1);
            csridx[beg + p] = (unsigned short)(pk >> 16);
        }
    } else {
        for (int i = tid; i < cnt; i += 256) {
            unsigned pk = pairs2[beg + i];
            int p = atomicAdd(&cur[pk & (BKT_NODES - 1)], 1);
            csridx[beg + p] = (unsigned short)(pk >> 16);
        }
    }
    if (b == nb - 1 && tid == 0) rowptr[n] = E;
}

// ------ Fused gather(mean, fp16 table) + dense (+relu / +L2 norm) -----------
// One wave per node. Gather: 16 lanes x 8 B (4 halves) per 128-B fp16 row,
// 4 edges in flight per VMEM issue. Root path + accumulate in fp32.
template <bool RELU, bool NORM, bool W16>
__global__ __launch_bounds__(256) void fused_sage_kernel(
    const int* __restrict__ rowptr, const unsigned short* __restrict__ csridx,
    const __half* __restrict__ src16, const float* __restrict__ src32,
    const float* __restrict__ W, const float* __restrict__ bvec,
    const float* __restrict__ R, float* __restrict__ out32,
    __half* __restrict__ out16, int n)
{
    __shared__ float Ws[FDIM][FDIM];
    __shared__ float Rs[FDIM][FDIM];
    __shared__ float bs[FDIM];
    __shared__ float aRow[4][FDIM];
    __shared__ float xRow[4][FDIM];
    int tid = threadIdx.x;
    for (int i = tid; i < FDIM * FDIM; i += 256) {
        Ws[i >> 6][i & 63] = W[i];
        Rs[i >> 6][i & 63] = R[i];
    }
    if (tid < FDIM) bs[tid] = bvec[tid];
    __syncthreads();

    int lane = tid & 63, w = tid >> 6;
    int g = lane >> 4;        // edge sub-group 0..3
    int q = lane & 15;        // 4-feature chunk within row

    for (int node = blockIdx.x * 4 + w; node < n; node += gridDim.x * 4) {
        int beg = rowptr[node], end = rowptr[node + 1];
        float4 s4 = make_float4(0.f, 0.f, 0.f, 0.f);
        for (int base = beg; base < end; base += 64) {
            int cnt = end - base; if (cnt > 64) cnt = 64;
            int ei = base + lane;
            int myidx = (ei < end) ? (int)csridx[ei] : 0;
            int steps = (cnt + 3) >> 2;
            for (int t = 0; t < steps; ++t) {
                int e = (t << 2) | g;
                int sidx = __shfl(myidx, e, 64);
                if (e < cnt) {
                    const float2* rp = (const float2*)(src16 + ((size_t)sidx << 6));
                    float2 vv = rp[q];                 // 4 halves = 8 B
                    __half2 ha = *reinterpret_cast<__half2*>(&vv.x);
                    __half2 hb = *reinterpret_cast<__half2*>(&vv.y);
                    float2 fa = __half22float2(ha);
                    float2 fb = __half22float2(hb);
                    s4.x += fa.x; s4.y += fa.y; s4.z += fb.x; s4.w += fb.y;
                }
            }
        }
#pragma unroll
        for (int o = 16; o < 64; o <<= 1) {
            s4.x += __shfl_xor(s4.x, o, 64);
            s4.y += __shfl_xor(s4.y, o, 64);
            s4.z += __shfl_xor(s4.z, o, 64);
            s4.w += __shfl_xor(s4.w, o, 64);
        }
        float dinv = 1.0f / fmaxf((float)(end - beg), 1.0f);
        if (g == 0) {
            aRow[w][q * 4 + 0] = s4.x * dinv;
            aRow[w][q * 4 + 1] = s4.y * dinv;
            aRow[w][q * 4 + 2] = s4.z * dinv;
            aRow[w][q * 4 + 3] = s4.w * dinv;
        }
        xRow[w][lane] = src32[((size_t)node << 6) + lane];
        float acc = bs[lane];
#pragma unroll
        for (int k = 0; k < FDIM; ++k)
            acc = fmaf(aRow[w][k], Ws[k][lane], fmaf(xRow[w][k], Rs[k][lane], acc));
        if (RELU) acc = fmaxf(acc, 0.0f);
        if (NORM) {
            float ss = acc * acc;
#pragma unroll
            for (int o = 32; o; o >>= 1) ss += __shfl_xor(ss, o, 64);
            acc *= 1.0f / fmaxf(sqrtf(ss), 1e-12f);
        }
        out32[((size_t)node << 6) + lane] = acc;
        if (W16) out16[((size_t)node << 6) + lane] = __float2half(acc);
    }
}

// ----------------- Atomic scatter path (fallback, 13.0 MB ws) ---------------
__global__ __launch_bounds__(256) void scatter_kernel(
    const float* __restrict__ src, const int* __restrict__ rows, const int* __restrict__ cols,
    float* __restrict__ agg, float* __restrict__ deg, int n, long long total)
{
    long long gid = (long long)blockIdx.x * 256 + threadIdx.x;
    if (gid >= total) return;
    int e = (int)(gid >> 6);
    int f = (int)(gid & 63);
    int r = clampi(rows[e], n), c = clampi(cols[e], n);
    atomicAdd(&agg[(long long)c * FDIM + f], src[(long long)r * FDIM + f]);
    if (f == 0) atomicAdd(&deg[c], 1.0f);
}

template <bool RELU, bool NORM>
__global__ __launch_bounds__(256) void dense_kernel(
    const float* __restrict__ agg, const float* __restrict__ deg, const float* __restrict__ x,
    const float* __restrict__ W, const float* __restrict__ b,
    const float* __restrict__ R, float* __restrict__ out, int n)
{
    __shared__ float Ws[FDIM][FDIM];
    __shared__ float Rs[FDIM][FDIM];
    __shared__ float bs[FDIM];
    __shared__ float aRow[4][FDIM];
    __shared__ float xRow[4][FDIM];
    int tid = threadIdx.x;
    for (int i = tid; i < FDIM * FDIM; i += 256) {
        Ws[i >> 6][i & 63] = W[i];
        Rs[i >> 6][i & 63] = R[i];
    }
    if (tid < FDIM) bs[tid] = b[tid];
    int j = tid & 63, r = tid >> 6;
    int row = blockIdx.x * 4 + r;
    if (row < n) {
        float d = fmaxf(deg[row], 1.0f);
        aRow[r][j] = agg[(long long)row * FDIM + j] / d;
        xRow[r][j] = x[(long long)row * FDIM + j];
    }
    __syncthreads();
    if (row >= n) return;
    float acc = bs[j];
#pragma unroll
    for (int k = 0; k < FDIM; ++k)
        acc = fmaf(aRow[r][k], Ws[k][j], fmaf(xRow[r][k], Rs[k][j], acc));
    if (RELU) acc = fmaxf(acc, 0.0f);
    if (NORM) {
        float ss = acc * acc;
#pragma unroll
        for (int o = 32; o; o >>= 1) ss += __shfl_xor(ss, o, 64);
        acc *= 1.0f / fmaxf(sqrtf(ss), 1e-12f);
    }
    out[(long long)row * FDIM + j] = acc;
}

// ---------------------------------------------------------------------------
extern "C" void kernel_launch(void* const* d_in, const int* in_sizes, int n_in,
                              void* d_out, int out_size, void* d_ws, size_t ws_size,
                              hipStream_t stream)
{
    const float* x  = (const float*)d_in[0];
    const int*   e0 = (const int*)d_in[1];
    const int*   e1 = (const int*)d_in[2];
    const float* W1 = (const float*)d_in[3];
    const float* b1 = (const float*)d_in[4];
    const float* R1 = (const float*)d_in[5];
    const float* W2 = (const float*)d_in[6];
    const float* b2 = (const float*)d_in[7];
    const float* R2 = (const float*)d_in[8];
    float* out = (float*)d_out;

    const int N = in_sizes[0] / FDIM;     // 50000
    const int E = in_sizes[1] / 2;        // 1600000

    const int nb = (N + BKT_NODES - 1) >> BKT_SHIFT;
    const int chunk = (E + NBLK_G - 1) / NBLK_G;
    const int FUSED_BLOCKS = 1024;

    // Workspace layout (byte offsets, 256-B aligned):
    // pairs2[E] u32 | blockcnt[NBLK_G*nb] | bucketBase[nb+1] | bucketTot[nb] |
    // rowptr[N+1] | x16[N*64] half | h16[N*64] half | csridx16[E] u16
    auto align256 = [](size_t v) { return (v + 255) & ~(size_t)255; };
    size_t off = 0;
    size_t o_pairs2 = off; off = align256(off + (size_t)E * 4);
    size_t o_bcnt   = off; off = align256(off + (size_t)NBLK_G * nb * 4);
    size_t o_bbase  = off; off = align256(off + (size_t)(nb + 1) * 4);
    size_t o_btot   = off; off = align256(off + (size_t)nb * 4);
    size_t o_rowp   = off; off = align256(off + (size_t)(N + 1) * 4);
    size_t o_x16    = off; off = align256(off + (size_t)N * FDIM * 2);
    size_t o_h16    = off; off = align256(off + (size_t)N * FDIM * 2);
    size_t o_csr16  = off; off = align256(off + (size_t)E * 2);
    const size_t need1 = off;

    const bool ok1 = (ws_size >= need1) && (N <= 65536) &&
                     (chunk <= CHUNK_CAP) && (nb <= NB_MAX);

    if (ok1) {
        char* wsb = (char*)d_ws;
        unsigned*        pairs2     = (unsigned*)(wsb + o_pairs2);
        int*             blockcnt   = (int*)(wsb + o_bcnt);
        int*             bucketBase = (int*)(wsb + o_bbase);
        int*             bucketTot  = (int*)(wsb + o_btot);
        int*             rowptr     = (int*)(wsb + o_rowp);
        __half*          x16        = (__half*)(wsb + o_x16);
        __half*          h16        = (__half*)(wsb + o_h16);
        unsigned short*  csridx     = (unsigned short*)(wsb + o_csr16);
        float*           h32        = out;   // layer-1 hidden lives in d_out

        convert_half<<<(N * FDIM + 255) / 256, 256, 0, stream>>>(x, x16, N * FDIM);

        // ---- Layer 1 ----
        p1a_hist<<<NBLK_G, 256, 0, stream>>>(e0 + E, blockcnt, N, E, nb, chunk);
        p2a_colscan<<<nb, 64, 0, stream>>>(blockcnt, bucketTot, nb, NBLK_G);
        p2b_basescan<<<1, 512, 0, stream>>>(bucketTot, bucketBase, nb);
        p3_binscatter<<<NBLK_G, 512, 0, stream>>>(e0, e0 + E, blockcnt, bucketBase,
                                                  pairs2, N, E, nb, chunk);
        p4_fine<<<nb, 256, 0, stream>>>(pairs2, bucketBase, rowptr, csridx, N, E, nb);
        fused_sage_kernel<true, false, true><<<FUSED_BLOCKS, 256, 0, stream>>>(
            rowptr, csridx, x16, x, W1, b1, R1, h32, h16, N);

        // ---- Layer 2 ----
        p1a_hist<<<NBLK_G, 256, 0, stream>>>(e1 + E, blockcnt, N, E, nb, chunk);
        p2a_colscan<<<nb, 64, 0, stream>>>(blockcnt, bucketTot, nb, NBLK_G);
        p2b_basescan<<<1, 512, 0, stream>>>(bucketTot, bucketBase, nb);
        p3_binscatter<<<NBLK_G, 512, 0, stream>>>(e1, e1 + E, blockcnt, bucketBase,
                                                  pairs2, N, E, nb, chunk);
        p4_fine<<<nb, 256, 0, stream>>>(pairs2, bucketBase, rowptr, csridx, N, E, nb);
        // in-place over d_out: each thread reads its own row before writing it
        fused_sage_kernel<false, true, false><<<FUSED_BLOCKS, 256, 0, stream>>>(
            rowptr, csridx, h16, h32, W2, b2, R2, out, (__half*)nullptr, N);
    } else {
        // Fallback: atomic scatter path (round-3, verified)
        float* agg = (float*)d_ws;
        float* deg = agg + (long long)N * FDIM;
        float* h = out;
        const long long total = (long long)E * FDIM;
        const int sblocks = (int)((total + 255) / 256);
        const int dblocks = (N + 3) / 4;

        hipMemsetAsync(agg, 0, ((size_t)N * FDIM + N) * sizeof(float), stream);
        scatter_kernel<<<sblocks, 256, 0, stream>>>(x, e0, e0 + E, agg, deg, N, total);
        dense_kernel<true, false><<<dblocks, 256, 0, stream>>>(agg, deg, x, W1, b1, R1, h, N);

        hipMemsetAsync(agg, 0, ((size_t)N * FDIM + N) * sizeof(float), stream);
        scatter_kernel<<<sblocks, 256, 0, stream>>>(h, e1, e1 + E, agg, deg, N, total);
        dense_kernel<false, true><<<dblocks, 256, 0, stream>>>(agg, deg, h, W2, b2, R2, out, N);
    }
}